// Round 4
// baseline (639.813 us; speedup 1.0000x reference)
//
#include <hip/hip_runtime.h>

#define THREADS 256
#define NWAVES 4
#define CAP 2048
#define SMALLCAP 128

constexpr int kV  = 32000;
constexpr int kV4 = kV / 4;   // 8000, divisible by 4

// One 256-thread block per row. Single streaming read pass collects a small
// superset of the sparsemax support (elements > running_wave_max - 1) into
// LDS as (value, index). tau computed exactly from the filtered/sorted
// candidates. Output = zeros streamed + scatter of the few support values
// (no second read of x, no register-resident row).
// Bisection fallback (reads x again) if candidate buffers overflow.
__global__ __launch_bounds__(THREADS, 8) void sparsemax_kernel(
    const float* __restrict__ in, float* __restrict__ out)
{
    const int row = blockIdx.x;
    const float* __restrict__ x = in + (size_t)row * kV;
    float* __restrict__ y = out + (size_t)row * kV;
    const int tid  = threadIdx.x;
    const int lane = tid & 63;
    const int wave = tid >> 6;

    __shared__ float s_val[CAP];
    __shared__ int   s_idx[CAP];
    __shared__ float s_small[SMALLCAP];
    __shared__ float s_sorted[SMALLCAP];
    __shared__ float s_red[NWAVES];
    __shared__ int   s_cnt;
    __shared__ int   s_n2;
    __shared__ float s_m;
    __shared__ float s_tau;
    __shared__ float s_sum;

    if (tid == 0) { s_cnt = 0; s_n2 = 0; }
    __syncthreads();

    const float4* __restrict__ x4 = reinterpret_cast<const float4*>(x);

    // ---- Pass 1: stream row, maintain per-wave running max, collect
    //      elements > wave_max - 1 (superset of support since wave_max <= m).
    float wthr = -3.4e38f;   // uniform across the wave after each group
    for (int g = 0; g < 8; ++g) {
        float4 v[4];
        float gmax = -3.4e38f;
        #pragma unroll
        for (int j = 0; j < 4; ++j) {
            const int i = (g * 4 + j) * THREADS + tid;
            if (i < kV4) {
                v[j] = x4[i];
                gmax = fmaxf(gmax, fmaxf(fmaxf(v[j].x, v[j].y), fmaxf(v[j].z, v[j].w)));
            } else {
                v[j] = make_float4(-3.4e38f, -3.4e38f, -3.4e38f, -3.4e38f);
            }
        }
        #pragma unroll
        for (int off = 32; off > 0; off >>= 1)
            gmax = fmaxf(gmax, __shfl_xor(gmax, off, 64));
        wthr = fmaxf(wthr, gmax);
        const float cut = wthr - 1.0f;
        #pragma unroll
        for (int j = 0; j < 4; ++j) {
            const int i = (g * 4 + j) * THREADS + tid;
            if (i < kV4) {
                const float a[4] = {v[j].x, v[j].y, v[j].z, v[j].w};
                #pragma unroll
                for (int c = 0; c < 4; ++c) {
                    if (a[c] > cut) {
                        int p = atomicAdd(&s_cnt, 1);
                        if (p < CAP) { s_val[p] = a[c]; s_idx[p] = i * 4 + c; }
                    }
                }
            }
        }
    }

    // ---- Block max ----
    if (lane == 0) s_red[wave] = wthr;
    __syncthreads();
    if (tid == 0)
        s_m = fmaxf(fmaxf(s_red[0], s_red[1]), fmaxf(s_red[2], s_red[3]));
    __syncthreads();
    const float m   = s_m;
    const int   cnt = s_cnt;

    if (cnt <= CAP) {
        // ---- Filter to true candidates z = v - m > -1 ----
        const float cutf = m - 1.0f;
        for (int c = tid; c < cnt; c += THREADS) {
            const float vv = s_val[c];
            if (vv > cutf) {
                int p = atomicAdd(&s_n2, 1);
                if (p < SMALLCAP) s_small[p] = vv - m;
            }
        }
        __syncthreads();
        const int n2 = s_n2;
        if (n2 <= SMALLCAP) {
            // ---- Rank-sort descending (unique ranks via index tiebreak) ----
            if (tid < n2) {
                const float zi = s_small[tid];
                int r = 0;
                for (int j = 0; j < n2; ++j) {
                    const float zj = s_small[j];
                    r += (zj > zi) || (zj == zi && j < tid);
                }
                s_sorted[r] = zi;
            }
            __syncthreads();
            if (tid == 0) {
                float cum = 0.0f, cumk = 0.0f;
                int k = 1;
                for (int j = 0; j < n2; ++j) {
                    cum += s_sorted[j];
                    if (1.0f + (float)(j + 1) * s_sorted[j] > cum) { k = j + 1; cumk = cum; }
                }
                s_tau = (cumk - 1.0f) / (float)k;
            }
            __syncthreads();
            const float thr = m + s_tau;

            // ---- Output: stream zeros, then scatter support values ----
            float4* __restrict__ y4 = reinterpret_cast<float4*>(y);
            const float4 zero = make_float4(0.0f, 0.0f, 0.0f, 0.0f);
            for (int i = tid; i < kV4; i += THREADS) y4[i] = zero;
            __syncthreads();   // drains stores (vmcnt 0) before scatter
            for (int c = tid; c < cnt; c += THREADS) {
                const float o = s_val[c] - thr;
                if (o > 0.0f) y[s_idx[c]] = o;
            }
            return;
        }
    }

    // ---- Fallback: bisection on tau in [-1,0] reading x (never hit here) ----
    {
        float lo = -1.0f, hi = 0.0f;
        for (int it = 0; it < 40; ++it) {
            const float mid = 0.5f * (lo + hi);
            float ls = 0.0f;
            for (int i = tid; i < kV4; i += THREADS) {
                const float4 vv = x4[i];
                ls += fmaxf(0.0f, vv.x - m - mid);
                ls += fmaxf(0.0f, vv.y - m - mid);
                ls += fmaxf(0.0f, vv.z - m - mid);
                ls += fmaxf(0.0f, vv.w - m - mid);
            }
            #pragma unroll
            for (int off = 32; off > 0; off >>= 1)
                ls += __shfl_xor(ls, off, 64);
            if (lane == 0) s_red[wave] = ls;
            __syncthreads();
            if (tid == 0) s_sum = s_red[0] + s_red[1] + s_red[2] + s_red[3];
            __syncthreads();
            const float s = s_sum;
            __syncthreads();
            if (s > 1.0f) lo = mid; else hi = mid;
        }
        const float thr = m + 0.5f * (lo + hi);
        float4* __restrict__ y4 = reinterpret_cast<float4*>(y);
        for (int i = tid; i < kV4; i += THREADS) {
            const float4 vv = x4[i];
            float4 o;
            o.x = fmaxf(0.0f, vv.x - thr);
            o.y = fmaxf(0.0f, vv.y - thr);
            o.z = fmaxf(0.0f, vv.z - thr);
            o.w = fmaxf(0.0f, vv.w - thr);
            y4[i] = o;
        }
    }
}

extern "C" void kernel_launch(void* const* d_in, const int* in_sizes, int n_in,
                              void* d_out, int out_size, void* d_ws, size_t ws_size,
                              hipStream_t stream) {
    const float* in = (const float*)d_in[0];
    float* out = (float*)d_out;
    const int B = in_sizes[0] / kV;
    sparsemax_kernel<<<B, THREADS, 0, stream>>>(in, out);
}

// Round 7
// 529.772 us; speedup vs baseline: 1.2077x; 1.2077x over previous
//
#include <hip/hip_runtime.h>

#define THREADS 256
#define CAP 1024
#define NEG_HUGE -3.0e38f

constexpr int kV  = 32000;
constexpr int kV4 = 8000;        // float4 per row
constexpr int GSZ = 4 * THREADS; // float4 per group = 1024

// One 256-thread block per row. Single streaming read with explicit
// double-buffered register prefetch (4 x float4 per buffer) and a pure
// per-thread running-max candidate cut (no cross-lane ops in hot loop).
// Seeds the cut from a one-time block max of group 0. Collects the
// sparsemax support superset (x > running_max - 1) into LDS, computes tau
// exactly from the sorted candidates, streams zeros during the read pass,
// scatters the few nonzeros at the end. Bisection fallback on overflow.
__global__ __launch_bounds__(THREADS, 6) void sparsemax_kernel(
    const float* __restrict__ in, float* __restrict__ out)
{
    const int row = blockIdx.x;
    const float4* __restrict__ x4 =
        reinterpret_cast<const float4*>(in + (size_t)row * kV);
    float4* __restrict__ y4 = reinterpret_cast<float4*>(out + (size_t)row * kV);
    float* __restrict__ y = out + (size_t)row * kV;
    const int tid  = threadIdx.x;
    const int lane = tid & 63;
    const int wave = tid >> 6;

    __shared__ float s_val[CAP];
    __shared__ int   s_idx[CAP];
    __shared__ float s_sorted[CAP];
    __shared__ float s_red[4];
    __shared__ int   s_cnt;
    __shared__ float s_tau;
    __shared__ float s_sum;

    if (tid == 0) s_cnt = 0;

    const float4 zero4 = make_float4(0.0f, 0.0f, 0.0f, 0.0f);

#define FMAX4(v) fmaxf(fmaxf((v).x, (v).y), fmaxf((v).z, (v).w))

    // ---- Preload groups 0 and 1 into register double-buffers ----
    float4 A0 = x4[0 * THREADS + tid];
    float4 A1 = x4[1 * THREADS + tid];
    float4 A2 = x4[2 * THREADS + tid];
    float4 A3 = x4[3 * THREADS + tid];
    float4 B0 = x4[GSZ + 0 * THREADS + tid];
    float4 B1 = x4[GSZ + 1 * THREADS + tid];
    float4 B2 = x4[GSZ + 2 * THREADS + tid];
    float4 B3 = x4[GSZ + 3 * THREADS + tid];

    // ---- Seed threshold: block max of group 0 (the only in-loop reduce) ----
    float lm = fmaxf(fmaxf(FMAX4(A0), FMAX4(A1)), fmaxf(FMAX4(A2), FMAX4(A3)));
    #pragma unroll
    for (int off = 32; off > 0; off >>= 1)
        lm = fmaxf(lm, __shfl_xor(lm, off, 64));
    if (lane == 0) s_red[wave] = lm;
    __syncthreads();   // also publishes s_cnt = 0
    float rmax = fmaxf(fmaxf(s_red[0], s_red[1]), fmaxf(s_red[2], s_red[3]));

#define PROC1(a, id) do {                                                   \
        if ((a) > cutc) {                                                   \
            int p = atomicAdd(&s_cnt, 1);                                   \
            if (p < CAP) { s_val[p] = (a); s_idx[p] = (id); }               \
        }                                                                   \
    } while (0)

#define PROC4(v, fid) do {                                                  \
        PROC1((v).x, 4 * (fid) + 0);                                        \
        PROC1((v).y, 4 * (fid) + 1);                                        \
        PROC1((v).z, 4 * (fid) + 2);                                        \
        PROC1((v).w, 4 * (fid) + 3);                                        \
        gm = fmaxf(gm, FMAX4(v));                                           \
    } while (0)

#define STEP(b0, b1, b2, b3, g) do {                                        \
        const float cutc = rmax - 1.0f;                                     \
        float gm = NEG_HUGE;                                                \
        y4[(g) * GSZ + 0 * THREADS + tid] = zero4;                          \
        y4[(g) * GSZ + 1 * THREADS + tid] = zero4;                          \
        y4[(g) * GSZ + 2 * THREADS + tid] = zero4;                          \
        y4[(g) * GSZ + 3 * THREADS + tid] = zero4;                          \
        PROC4(b0, (g) * GSZ + 0 * THREADS + tid);                           \
        PROC4(b1, (g) * GSZ + 1 * THREADS + tid);                          \
        PROC4(b2, (g) * GSZ + 2 * THREADS + tid);                          \
        PROC4(b3, (g) * GSZ + 3 * THREADS + tid);                          \
        rmax = fmaxf(rmax, gm);                                             \
    } while (0)

#define STEP7(b0, b1, b2, b3) do {                                          \
        const float cutc = rmax - 1.0f;                                     \
        float gm = NEG_HUGE;                                                \
        y4[7 * GSZ + 0 * THREADS + tid] = zero4;                            \
        y4[7 * GSZ + 1 * THREADS + tid] = zero4;                            \
        y4[7 * GSZ + 2 * THREADS + tid] = zero4;                            \
        if (7 * GSZ + 3 * THREADS + tid < kV4)                              \
            y4[7 * GSZ + 3 * THREADS + tid] = zero4;                        \
        PROC4(b0, 7 * GSZ + 0 * THREADS + tid);                             \
        PROC4(b1, 7 * GSZ + 1 * THREADS + tid);                             \
        PROC4(b2, 7 * GSZ + 2 * THREADS + tid);                             \
        PROC4(b3, 7 * GSZ + 3 * THREADS + tid);                             \
        rmax = fmaxf(rmax, gm);                                             \
    } while (0)

#define LOADA(g) do {                                                       \
        A0 = x4[(g) * GSZ + 0 * THREADS + tid];                             \
        A1 = x4[(g) * GSZ + 1 * THREADS + tid];                             \
        A2 = x4[(g) * GSZ + 2 * THREADS + tid];                             \
        A3 = x4[(g) * GSZ + 3 * THREADS + tid];                             \
    } while (0)

#define LOADB(g) do {                                                       \
        B0 = x4[(g) * GSZ + 0 * THREADS + tid];                             \
        B1 = x4[(g) * GSZ + 1 * THREADS + tid];                             \
        B2 = x4[(g) * GSZ + 2 * THREADS + tid];                             \
        B3 = x4[(g) * GSZ + 3 * THREADS + tid];                             \
    } while (0)

    // ---- Main pipeline: process cur, prefetch group g+2 into freed regs.
    // Per-thread running-max cut only (cut <= m-1 always => support superset).
    STEP(A0, A1, A2, A3, 0); LOADA(2);
    STEP(B0, B1, B2, B3, 1); LOADB(3);
    STEP(A0, A1, A2, A3, 2); LOADA(4);
    STEP(B0, B1, B2, B3, 3); LOADB(5);
    STEP(A0, A1, A2, A3, 4); LOADA(6);
    STEP(B0, B1, B2, B3, 5);
    // group 7 load: last float4 slot guarded (7936 + tid < 8000 iff tid < 64)
    B0 = x4[7 * GSZ + 0 * THREADS + tid];
    B1 = x4[7 * GSZ + 1 * THREADS + tid];
    B2 = x4[7 * GSZ + 2 * THREADS + tid];
    {
        const int id3 = 7 * GSZ + 3 * THREADS + tid;
        B3 = (id3 < kV4) ? x4[id3]
                         : make_float4(NEG_HUGE, NEG_HUGE, NEG_HUGE, NEG_HUGE);
    }
    STEP(A0, A1, A2, A3, 6);
    STEP7(B0, B1, B2, B3);   // NEG_HUGE lanes never pass the cut

    // ---- Final block max (exact row max m) + fence collection ----
    #pragma unroll
    for (int off = 32; off > 0; off >>= 1)
        rmax = fmaxf(rmax, __shfl_xor(rmax, off, 64));
    if (lane == 0) s_red[wave] = rmax;
    __syncthreads();
    const float m = fmaxf(fmaxf(s_red[0], s_red[1]), fmaxf(s_red[2], s_red[3]));
    const int cnt = s_cnt;

    if (cnt <= CAP) {
        // ---- Rank-sort candidates descending (index tiebreak => unique ranks)
        for (int i = tid; i < cnt; i += THREADS) {
            const float vi = s_val[i];
            int r = 0;
            for (int j = 0; j < cnt; ++j) {
                const float vj = s_val[j];
                r += (vj > vi) || (vj == vi && j < i);
            }
            s_sorted[r] = vi - m;
        }
        __syncthreads();
        if (tid == 0) {
            float cum = 0.0f, cumk = 0.0f;
            int k = 1;
            for (int j = 0; j < cnt; ++j) {
                cum += s_sorted[j];
                if (1.0f + (float)(j + 1) * s_sorted[j] > cum) { k = j + 1; cumk = cum; }
            }
            s_tau = (cumk - 1.0f) / (float)k;
        }
        __syncthreads();
        const float thr = m + s_tau;

        // Zeros were streamed during the read pass and drained at the
        // barriers above; scatter the support values now.
        for (int c = tid; c < cnt; c += THREADS) {
            const float o = s_val[c] - thr;
            if (o > 0.0f) y[s_idx[c]] = o;
        }
        return;
    }

    // ---- Fallback: bisection on tau in [-1,0], re-reading x (never hit) ----
    {
        float lo = -1.0f, hi = 0.0f;
        for (int it = 0; it < 40; ++it) {
            const float mid = 0.5f * (lo + hi);
            float ls = 0.0f;
            for (int i = tid; i < kV4; i += THREADS) {
                const float4 vv = x4[i];
                ls += fmaxf(0.0f, vv.x - m - mid);
                ls += fmaxf(0.0f, vv.y - m - mid);
                ls += fmaxf(0.0f, vv.z - m - mid);
                ls += fmaxf(0.0f, vv.w - m - mid);
            }
            #pragma unroll
            for (int off = 32; off > 0; off >>= 1)
                ls += __shfl_xor(ls, off, 64);
            if (lane == 0) s_red[wave] = ls;
            __syncthreads();
            if (tid == 0) s_sum = s_red[0] + s_red[1] + s_red[2] + s_red[3];
            __syncthreads();
            const float s = s_sum;
            __syncthreads();
            if (s > 1.0f) lo = mid; else hi = mid;
        }
        const float thr = m + 0.5f * (lo + hi);
        for (int i = tid; i < kV4; i += THREADS) {
            const float4 vv = x4[i];
            float4 o;
            o.x = fmaxf(0.0f, vv.x - thr);
            o.y = fmaxf(0.0f, vv.y - thr);
            o.z = fmaxf(0.0f, vv.z - thr);
            o.w = fmaxf(0.0f, vv.w - thr);
            y4[i] = o;
        }
    }
}

extern "C" void kernel_launch(void* const* d_in, const int* in_sizes, int n_in,
                              void* d_out, int out_size, void* d_ws, size_t ws_size,
                              hipStream_t stream) {
    const float* in = (const float*)d_in[0];
    float* out = (float*)d_out;
    const int B = in_sizes[0] / kV;
    sparsemax_kernel<<<B, THREADS, 0, stream>>>(in, out);
}